// Round 4
// baseline (7798.090 us; speedup 1.0000x reference)
//
#include <hip/hip_runtime.h>

#define NY 512
#define NX 512
#define NSHOT 4
#define NSRC 2
#define NREC 64
#define NT 32
#define DXF 5.0f
#define DTF 0.0005f
#define PML_W 20
#define C1F 1.125f
#define C2F (-1.0f/24.0f)

// 512 persistent blocks: 4 shots x 128 bands x 4 rows. Neighbor-only sync:
// stencil reach is +-2 rows < 4-row band, so each block waits only on its two
// adjacent bands (monotonic epoch flags), never on the whole grid.
#define NBLK 512
#define BLK_PER_SHOT 128
#define ROWS_PER_BLK 4
#define FPAD 4   // flag stride in u32 (16 B)

struct Params {
    const float *lamb, *mu, *buoy, *amps;
    const int *srcloc, *recloc;
    float *out, *pa, *pb;
    unsigned *flags;
    float *vy, *vx, *syy, *sxy, *sxx;
    float *m_vyy, *m_vyx, *m_vxy, *m_vxx;
    float *m_syyy, *m_sxyy, *m_sxyx, *m_sxxx;
};

// PML strips: sigma>0 (a!=0) only for index < 20 or >= NY-20. Outside, m stays 0.
__device__ __forceinline__ bool in_pml(int i) {
    return (i < PML_W) | (i >= NY - PML_W);
}

__device__ __forceinline__ float ldz(const float* __restrict__ f, int sbase, int y, int x) {
    return ((unsigned)y < (unsigned)NY && (unsigned)x < (unsigned)NX)
               ? f[sbase + y * NX + x] : 0.0f;
}

__global__ void init_profiles(float* __restrict__ pa, float* __restrict__ pb) {
    int i = blockIdx.x * blockDim.x + threadIdx.x;
    if (i >= NY) return;
    float w = (float)PML_W;
    float x = (float)i;
    float frac = fmaxf((w - x) / w, (x - (float)(NY - 1 - PML_W)) / w);
    frac = fminf(fmaxf(frac, 0.0f), 1.0f);
    float sigma = 3.0f * 3500.0f * 6.9077553f / (2.0f * w * DXF) * frac * frac;
    float alpha = 78.539816f; // pi * 25
    float b = __expf(-(sigma + alpha) * DTF);
    pb[i] = b;
    pa[i] = sigma / (sigma + alpha) * (b - 1.0f);
}

// publish: all block stores drained (syncthreads -> per-thread vmcnt(0)),
// then one agent-release fence (L2 writeback to coherent LLC) + flag store.
__device__ __forceinline__ void publish(unsigned* flags, int bid, unsigned e) {
    __syncthreads();
    if (threadIdx.x == 0) {
        __threadfence();
        __hip_atomic_store(&flags[bid * FPAD], e, __ATOMIC_RELEASE, __HIP_MEMORY_SCOPE_AGENT);
    }
}

// wait: spin on neighbor epochs with agent-scope loads, then acquire fence
// (L1/L2 invalidate) so stale halo lines are not served from local caches.
__device__ __forceinline__ void wait_nbrs(unsigned* flags, int bl, int br, unsigned e) {
    if (threadIdx.x == 0 && bl >= 0) {
        while (__hip_atomic_load(&flags[bl * FPAD], __ATOMIC_ACQUIRE, __HIP_MEMORY_SCOPE_AGENT) < e)
            __builtin_amdgcn_s_sleep(2);
    }
    if (threadIdx.x == 1 && br >= 0) {
        while (__hip_atomic_load(&flags[br * FPAD], __ATOMIC_ACQUIRE, __HIP_MEMORY_SCOPE_AGENT) < e)
            __builtin_amdgcn_s_sleep(2);
    }
    __threadfence();
    __syncthreads();
}

__device__ __forceinline__ void vel_cell(const Params& P, int s, int y, int x, int t) {
    const float* __restrict__ syy = P.syy;
    const float* __restrict__ sxy = P.sxy;
    const float* __restrict__ sxx = P.sxx;
    int sbase = s * NY * NX;
    int idx = sbase + y * NX + x;
    const float inv_dx = 1.0f / DXF;

    // dsyy = diff_minus(syy, y): taps y-2..y+1
    float syy_0  = syy[idx];
    float syy_m1 = ldz(syy, sbase, y - 1, x);
    float syy_m2 = ldz(syy, sbase, y - 2, x);
    float syy_p1 = ldz(syy, sbase, y + 1, x);
    float dsyy = (C1F * (syy_0 - syy_m1) + C2F * (syy_p1 - syy_m2)) * inv_dx;

    // dsxy_x = diff_plus(sxy, x): taps x-1..x+2
    float sxy_0   = sxy[idx];
    float sxy_xm1 = ldz(sxy, sbase, y, x - 1);
    float sxy_xp1 = ldz(sxy, sbase, y, x + 1);
    float sxy_xp2 = ldz(sxy, sbase, y, x + 2);
    float dsxy_x = (C1F * (sxy_xp1 - sxy_0) + C2F * (sxy_xp2 - sxy_xm1)) * inv_dx;

    // dsxy_y = diff_plus(sxy, y): taps y-1..y+2
    float sxy_ym1 = ldz(sxy, sbase, y - 1, x);
    float sxy_yp1 = ldz(sxy, sbase, y + 1, x);
    float sxy_yp2 = ldz(sxy, sbase, y + 2, x);
    float dsxy_y = (C1F * (sxy_yp1 - sxy_0) + C2F * (sxy_yp2 - sxy_ym1)) * inv_dx;

    // dsxx = diff_minus(sxx, x): taps x-2..x+1
    float sxx_0   = sxx[idx];
    float sxx_xm1 = ldz(sxx, sbase, y, x - 1);
    float sxx_xm2 = ldz(sxx, sbase, y, x - 2);
    float sxx_xp1 = ldz(sxx, sbase, y, x + 1);
    float dsxx = (C1F * (sxx_0 - sxx_xm1) + C2F * (sxx_xp1 - sxx_xm2)) * inv_dx;

    float msyyy = 0.0f, msxyy = 0.0f;
    if (in_pml(y)) {
        float ay = P.pa[y], by = P.pb[y];
        msyyy = by * P.m_syyy[idx] + ay * dsyy;   P.m_syyy[idx] = msyyy;
        msxyy = by * P.m_sxyy[idx] + ay * dsxy_y; P.m_sxyy[idx] = msxyy;
    }
    float msxyx = 0.0f, msxxx = 0.0f;
    if (in_pml(x)) {
        float ax = P.pa[x], bx = P.pb[x];
        msxyx = bx * P.m_sxyx[idx] + ax * dsxy_x; P.m_sxyx[idx] = msxyx;
        msxxx = bx * P.m_sxxx[idx] + ax * dsxx;   P.m_sxxx[idx] = msxxx;
    }

    float b = P.buoy[y * NX + x];
    float vy_new = P.vy[idx] + DTF * b * ((dsyy + msyyy) + (dsxy_x + msxyx));
    P.vx[idx] += DTF * b * ((dsxy_y + msxyy) + (dsxx + msxxx));

#pragma unroll
    for (int i = 0; i < NSRC; ++i) {
        int sy = P.srcloc[(s * NSRC + i) * 2 + 0];
        int sx = P.srcloc[(s * NSRC + i) * 2 + 1];
        if (sy == y && sx == x) {
            vy_new += P.amps[(s * NSRC + i) * NT + t] * DTF * b;
        }
    }
    P.vy[idx] = vy_new;
}

__device__ __forceinline__ void stress_cell(const Params& P, int s, int y, int x) {
    const float* __restrict__ vy = P.vy;
    const float* __restrict__ vx = P.vx;
    int sbase = s * NY * NX;
    int idx = sbase + y * NX + x;
    const float inv_dx = 1.0f / DXF;

    // dvyy = diff_plus(vy, y)
    float vy_0   = vy[idx];
    float vy_ym1 = ldz(vy, sbase, y - 1, x);
    float vy_yp1 = ldz(vy, sbase, y + 1, x);
    float vy_yp2 = ldz(vy, sbase, y + 2, x);
    float dvyy = (C1F * (vy_yp1 - vy_0) + C2F * (vy_yp2 - vy_ym1)) * inv_dx;

    // dvxx = diff_plus(vx, x)
    float vx_0   = vx[idx];
    float vx_xm1 = ldz(vx, sbase, y, x - 1);
    float vx_xp1 = ldz(vx, sbase, y, x + 1);
    float vx_xp2 = ldz(vx, sbase, y, x + 2);
    float dvxx = (C1F * (vx_xp1 - vx_0) + C2F * (vx_xp2 - vx_xm1)) * inv_dx;

    // dvyx = diff_minus(vy, x)
    float vy_xm1 = ldz(vy, sbase, y, x - 1);
    float vy_xm2 = ldz(vy, sbase, y, x - 2);
    float vy_xp1 = ldz(vy, sbase, y, x + 1);
    float dvyx = (C1F * (vy_0 - vy_xm1) + C2F * (vy_xp1 - vy_xm2)) * inv_dx;

    // dvxy = diff_minus(vx, y)
    float vx_ym1 = ldz(vx, sbase, y - 1, x);
    float vx_ym2 = ldz(vx, sbase, y - 2, x);
    float vx_yp1 = ldz(vx, sbase, y + 1, x);
    float dvxy = (C1F * (vx_0 - vx_ym1) + C2F * (vx_yp1 - vx_ym2)) * inv_dx;

    float mvyy = 0.0f, mvxy = 0.0f;
    if (in_pml(y)) {
        float ay = P.pa[y], by = P.pb[y];
        mvyy = by * P.m_vyy[idx] + ay * dvyy; P.m_vyy[idx] = mvyy;
        mvxy = by * P.m_vxy[idx] + ay * dvxy; P.m_vxy[idx] = mvxy;
    }
    float mvxx = 0.0f, mvyx = 0.0f;
    if (in_pml(x)) {
        float ax = P.pa[x], bx = P.pb[x];
        mvxx = bx * P.m_vxx[idx] + ax * dvxx; P.m_vxx[idx] = mvxx;
        mvyx = bx * P.m_vyx[idx] + ax * dvyx; P.m_vyx[idx] = mvyx;
    }

    float tvyy = dvyy + mvyy;
    float tvxx = dvxx + mvxx;

    float la = P.lamb[y * NX + x];
    float m  = P.mu[y * NX + x];
    float l2m = la + 2.0f * m;
    P.syy[idx] += DTF * (l2m * tvyy + la * tvxx);
    P.sxx[idx] += DTF * (l2m * tvxx + la * tvyy);
    P.sxy[idx] += DTF * m * ((dvyx + mvyx) + (dvxy + mvxy));
}

__global__ __launch_bounds__(256) void fdtd_persistent(Params P) {
    const int bid  = blockIdx.x;
    const int s    = bid / BLK_PER_SHOT;
    const int band = bid % BLK_PER_SHOT;
    const int y0   = band * ROWS_PER_BLK;
    const int tid  = threadIdx.x;
    unsigned* flags = P.flags;
    const int bl = (band > 0) ? bid - 1 : -1;
    const int br = (band < BLK_PER_SHOT - 1) ? bid + 1 : -1;

    for (int t = 0; t < NT; ++t) {
        // need neighbors' stress of step t-1 done (epoch 2t; trivially true at t=0)
        wait_nbrs(flags, bl, br, 2u * t);

        // ---- velocity phase on own 4-row band ----
#pragma unroll
        for (int c = 0; c < 2 * ROWS_PER_BLK; ++c) {
            int y = y0 + (c >> 1);
            int x = ((c & 1) << 8) + tid;
            vel_cell(P, s, y, x, t);
        }
        publish(flags, bid, 2u * t + 1u);

        // receivers whose row lies in our band (vy is block-local, post-sync)
        if (tid < NREC) {
            int ry = P.recloc[(s * NREC + tid) * 2 + 0];
            int rx = P.recloc[(s * NREC + tid) * 2 + 1];
            if (ry >= y0 && ry < y0 + ROWS_PER_BLK)
                P.out[(s * NREC + tid) * NT + t] = P.vy[s * NY * NX + ry * NX + rx];
        }

        // need neighbors' velocity of step t done (epoch 2t+1)
        wait_nbrs(flags, bl, br, 2u * t + 1u);

        // ---- stress phase on own 4-row band ----
#pragma unroll
        for (int c = 0; c < 2 * ROWS_PER_BLK; ++c) {
            int y = y0 + (c >> 1);
            int x = ((c & 1) << 8) + tid;
            stress_cell(P, s, y, x);
        }
        publish(flags, bid, 2u * t + 2u);
    }
}

extern "C" void kernel_launch(void* const* d_in, const int* in_sizes, int n_in,
                              void* d_out, int out_size, void* d_ws, size_t ws_size,
                              hipStream_t stream) {
    unsigned* flags = (unsigned*)d_ws;              // NBLK * FPAD u32 = 8 KB
    float* pa = (float*)d_ws + NBLK * FPAD;
    float* pb = pa + 512;
    float* fields = pb + 512;
    const size_t F = (size_t)NSHOT * NY * NX;

    Params P;
    P.lamb   = (const float*)d_in[0];
    P.mu     = (const float*)d_in[1];
    P.buoy   = (const float*)d_in[2];
    P.amps   = (const float*)d_in[3];
    P.srcloc = (const int*)d_in[4];
    P.recloc = (const int*)d_in[5];
    P.out    = (float*)d_out;
    P.pa = pa; P.pb = pb; P.flags = flags;
    P.vy     = fields + 0  * F;
    P.vx     = fields + 1  * F;
    P.syy    = fields + 2  * F;
    P.sxy    = fields + 3  * F;
    P.sxx    = fields + 4  * F;
    P.m_vyy  = fields + 5  * F;
    P.m_vyx  = fields + 6  * F;
    P.m_vxy  = fields + 7  * F;
    P.m_vxx  = fields + 8  * F;
    P.m_syyy = fields + 9  * F;
    P.m_sxyy = fields + 10 * F;
    P.m_sxyx = fields + 11 * F;
    P.m_sxxx = fields + 12 * F;

    // zero flags + profiles + all 13 state fields (ws is poisoned 0xAA)
    size_t zero_bytes = (size_t)(NBLK * FPAD) * 4 + 1024 * 4 + 13 * F * 4;
    hipMemsetAsync(d_ws, 0, zero_bytes, stream);
    init_profiles<<<2, 256, 0, stream>>>(pa, pb);

    fdtd_persistent<<<dim3(NBLK), dim3(256), 0, stream>>>(P);
}

// Round 5
// 1283.492 us; speedup vs baseline: 6.0757x; 6.0757x over previous
//
#include <hip/hip_runtime.h>

#define NY 512
#define NX 512
#define NSHOT 4
#define NSRC 2
#define NREC 64
#define NT 32
#define DXF 5.0f
#define DTF 0.0005f
#define PML_W 20
#define C1F 1.125f
#define C2F (-1.0f/24.0f)

// One fused kernel per timestep. Band decomposition: 4 shots x 64 bands x 8 rows,
// 256 blocks (1/CU) x 512 threads (thread = x column). Velocity is computed on an
// extended band (rows y0-2..y0+9) into LDS, so the stress phase needs no neighbor's
// velocity writes. All fields read across block boundaries are ping-ponged, so a
// launch boundary (cheap HW barrier + cache maintenance) is the only sync.
// PML m-fields live in compact strip arrays (sigma==0 -> m==0 outside strips).
#define RB 8          // interior rows per block
#define EB 12         // extended rows (RB + 4)
#define BANDS 64
#define NBLK (NSHOT * BANDS)

struct SP {
    const float *lamb, *mu, *buoy, *amps;
    const int *srcloc, *recloc;
    float *out;
    const float *pa, *pb;
    // ping-pong: read old, write new (interior cells only)
    const float *vy_o, *vx_o, *syy_o, *sxy_o, *sxx_o;
    float *vy_n, *vx_n, *syy_n, *sxy_n, *sxx_n;
    const float *msyyy_o, *msxyy_o;   // y-strips [shot][40][512]
    float *msyyy_n, *msxyy_n;
    const float *msxyx_o, *msxxx_o;   // x-strips [shot][512][40]
    float *msxyx_n, *msxxx_n;
    // owner-only, pointwise -> single buffer
    float *mvyy, *mvxy;               // y-strips
    float *mvyx, *mvxx;               // x-strips
};

__device__ __forceinline__ bool in_pml(int i) {
    return (i < PML_W) | (i >= NY - PML_W);
}

__device__ __forceinline__ float ldz(const float* __restrict__ f, int sbase, int y, int x) {
    return ((unsigned)y < (unsigned)NY && (unsigned)x < (unsigned)NX)
               ? f[sbase + y * NX + x] : 0.0f;
}

__global__ void init_profiles(float* __restrict__ pa, float* __restrict__ pb) {
    int i = blockIdx.x * blockDim.x + threadIdx.x;
    if (i >= NY) return;
    float w = (float)PML_W;
    float x = (float)i;
    float frac = fmaxf((w - x) / w, (x - (float)(NY - 1 - PML_W)) / w);
    frac = fminf(fmaxf(frac, 0.0f), 1.0f);
    float sigma = 3.0f * 3500.0f * 6.9077553f / (2.0f * w * DXF) * frac * frac;
    float alpha = 78.539816f; // pi * 25
    float b = __expf(-(sigma + alpha) * DTF);
    pb[i] = b;
    pa[i] = sigma / (sigma + alpha) * (b - 1.0f);
}

__global__ __launch_bounds__(512) void step_kernel(SP p, int t) {
    const int blk  = blockIdx.x;
    const int s    = blk >> 6;        // shot
    const int band = blk & (BANDS - 1);
    const int y0   = band * RB;
    const int x    = threadIdx.x;     // 0..511
    const int sbase = s * NY * NX;
    const float inv_dx = 1.0f / DXF;

    __shared__ float vyt[EB][NX];
    __shared__ float vxt[EB][NX];

    const float axp = p.pa[x], bxp = p.pb[x];
    const bool  xpml = in_pml(x);
    const int   xsi  = (x < PML_W) ? x : x - (NY - 2 * PML_W);  // 0..39

    // ---- phase A: velocity on extended rows [y0-2, y0+RB+2) ----
    for (int r = 0; r < EB; ++r) {
        int y = y0 - 2 + r;
        float vyn = 0.0f, vxn = 0.0f;
        if ((unsigned)y < (unsigned)NY) {
            int idx = sbase + y * NX + x;

            // dsyy = diff_minus(syy, y): taps y-2..y+1
            float syy_0  = p.syy_o[idx];
            float syy_m1 = ldz(p.syy_o, sbase, y - 1, x);
            float syy_m2 = ldz(p.syy_o, sbase, y - 2, x);
            float syy_p1 = ldz(p.syy_o, sbase, y + 1, x);
            float dsyy = (C1F * (syy_0 - syy_m1) + C2F * (syy_p1 - syy_m2)) * inv_dx;

            // dsxy_x = diff_plus(sxy, x): taps x-1..x+2
            float sxy_0   = p.sxy_o[idx];
            float sxy_xm1 = ldz(p.sxy_o, sbase, y, x - 1);
            float sxy_xp1 = ldz(p.sxy_o, sbase, y, x + 1);
            float sxy_xp2 = ldz(p.sxy_o, sbase, y, x + 2);
            float dsxy_x = (C1F * (sxy_xp1 - sxy_0) + C2F * (sxy_xp2 - sxy_xm1)) * inv_dx;

            // dsxy_y = diff_plus(sxy, y): taps y-1..y+2
            float sxy_ym1 = ldz(p.sxy_o, sbase, y - 1, x);
            float sxy_yp1 = ldz(p.sxy_o, sbase, y + 1, x);
            float sxy_yp2 = ldz(p.sxy_o, sbase, y + 2, x);
            float dsxy_y = (C1F * (sxy_yp1 - sxy_0) + C2F * (sxy_yp2 - sxy_ym1)) * inv_dx;

            // dsxx = diff_minus(sxx, x): taps x-2..x+1
            float sxx_0   = p.sxx_o[idx];
            float sxx_xm1 = ldz(p.sxx_o, sbase, y, x - 1);
            float sxx_xm2 = ldz(p.sxx_o, sbase, y, x - 2);
            float sxx_xp1 = ldz(p.sxx_o, sbase, y, x + 1);
            float dsxx = (C1F * (sxx_0 - sxx_xm1) + C2F * (sxx_xp1 - sxx_xm2)) * inv_dx;

            bool own = (y >= y0) & (y < y0 + RB);

            float msyyy = 0.0f, msxyy = 0.0f;
            if (in_pml(y)) {
                int ysi = (y < PML_W) ? y : y - (NY - 2 * PML_W);
                int is = (s * 2 * PML_W + ysi) * NX + x;
                float ay = p.pa[y], by = p.pb[y];
                msyyy = by * p.msyyy_o[is] + ay * dsyy;
                msxyy = by * p.msxyy_o[is] + ay * dsxy_y;
                if (own) { p.msyyy_n[is] = msyyy; p.msxyy_n[is] = msxyy; }
            }
            float msxyx = 0.0f, msxxx = 0.0f;
            if (xpml) {
                int is = (s * NY + y) * 2 * PML_W + xsi;
                msxyx = bxp * p.msxyx_o[is] + axp * dsxy_x;
                msxxx = bxp * p.msxxx_o[is] + axp * dsxx;
                if (own) { p.msxyx_n[is] = msxyx; p.msxxx_n[is] = msxxx; }
            }

            float b = p.buoy[y * NX + x];
            vyn = p.vy_o[idx] + DTF * b * ((dsyy + msyyy) + (dsxy_x + msxyx));
            vxn = p.vx_o[idx] + DTF * b * ((dsxy_y + msxyy) + (dsxx + msxxx));

            // source injection (also on redundantly-computed halo rows)
#pragma unroll
            for (int i = 0; i < NSRC; ++i) {
                int sy = p.srcloc[(s * NSRC + i) * 2 + 0];
                int sx = p.srcloc[(s * NSRC + i) * 2 + 1];
                if (sy == y && sx == x)
                    vyn += p.amps[(s * NSRC + i) * NT + t] * DTF * b;
            }
            if (own) { p.vy_n[idx] = vyn; p.vx_n[idx] = vxn; }
        }
        vyt[r][x] = vyn;
        vxt[r][x] = vxn;
    }
    __syncthreads();

    // ---- receivers for this step: vy(t) post-injection, owner band only ----
    if (x < NREC) {
        int ry = p.recloc[(s * NREC + x) * 2 + 0];
        int rx = p.recloc[(s * NREC + x) * 2 + 1];
        if (ry >= y0 && ry < y0 + RB)
            p.out[(s * NREC + x) * NT + t] = vyt[ry - y0 + 2][rx];
    }

    // ---- phase B: stress on interior rows, velocities from LDS ----
    for (int r = 0; r < RB; ++r) {
        int y  = y0 + r;
        int lr = r + 2;
        int idx = sbase + y * NX + x;

        float vy0v = vyt[lr][x];
        float dvyy = (C1F * (vyt[lr + 1][x] - vy0v) + C2F * (vyt[lr + 2][x] - vyt[lr - 1][x])) * inv_dx;

        float vx0v = vxt[lr][x];
        float vx_xm1 = (x >= 1)   ? vxt[lr][x - 1] : 0.0f;
        float vx_xp1 = (x <= 510) ? vxt[lr][x + 1] : 0.0f;
        float vx_xp2 = (x <= 509) ? vxt[lr][x + 2] : 0.0f;
        float dvxx = (C1F * (vx_xp1 - vx0v) + C2F * (vx_xp2 - vx_xm1)) * inv_dx;

        float vy_xm1 = (x >= 1)   ? vyt[lr][x - 1] : 0.0f;
        float vy_xm2 = (x >= 2)   ? vyt[lr][x - 2] : 0.0f;
        float vy_xp1 = (x <= 510) ? vyt[lr][x + 1] : 0.0f;
        float dvyx = (C1F * (vy0v - vy_xm1) + C2F * (vy_xp1 - vy_xm2)) * inv_dx;

        float dvxy = (C1F * (vx0v - vxt[lr - 1][x]) + C2F * (vxt[lr + 1][x] - vxt[lr - 2][x])) * inv_dx;

        float mvyy = 0.0f, mvxy = 0.0f;
        if (in_pml(y)) {
            int ysi = (y < PML_W) ? y : y - (NY - 2 * PML_W);
            int is = (s * 2 * PML_W + ysi) * NX + x;
            float ay = p.pa[y], by = p.pb[y];
            mvyy = by * p.mvyy[is] + ay * dvyy; p.mvyy[is] = mvyy;
            mvxy = by * p.mvxy[is] + ay * dvxy; p.mvxy[is] = mvxy;
        }
        float mvxx = 0.0f, mvyx = 0.0f;
        if (xpml) {
            int is = (s * NY + y) * 2 * PML_W + xsi;
            mvxx = bxp * p.mvxx[is] + axp * dvxx; p.mvxx[is] = mvxx;
            mvyx = bxp * p.mvyx[is] + axp * dvyx; p.mvyx[is] = mvyx;
        }

        float tvyy = dvyy + mvyy;
        float tvxx = dvxx + mvxx;
        float la = p.lamb[y * NX + x];
        float m  = p.mu[y * NX + x];
        float l2m = la + 2.0f * m;
        p.syy_n[idx] = p.syy_o[idx] + DTF * (l2m * tvyy + la * tvxx);
        p.sxx_n[idx] = p.sxx_o[idx] + DTF * (l2m * tvxx + la * tvyy);
        p.sxy_n[idx] = p.sxy_o[idx] + DTF * m * ((dvyx + mvyx) + (dvxy + mvxy));
    }
}

extern "C" void kernel_launch(void* const* d_in, const int* in_sizes, int n_in,
                              void* d_out, int out_size, void* d_ws, size_t ws_size,
                              hipStream_t stream) {
    const size_t F  = (size_t)NSHOT * NY * NX;            // full field
    const size_t SY = (size_t)NSHOT * 2 * PML_W * NX;     // y-strip field
    const size_t SX = (size_t)NSHOT * NY * 2 * PML_W;     // x-strip field

    float* w = (float*)d_ws;
    float* pa = w; w += 512;
    float* pb = w; w += 512;
    float* vy[2];  float* vx[2];  float* syy[2]; float* sxy[2]; float* sxx[2];
    float* msyyy[2]; float* msxyy[2]; float* msxyx[2]; float* msxxx[2];
    for (int i = 0; i < 2; ++i) { vy[i]  = w; w += F; }
    for (int i = 0; i < 2; ++i) { vx[i]  = w; w += F; }
    for (int i = 0; i < 2; ++i) { syy[i] = w; w += F; }
    for (int i = 0; i < 2; ++i) { sxy[i] = w; w += F; }
    for (int i = 0; i < 2; ++i) { sxx[i] = w; w += F; }
    for (int i = 0; i < 2; ++i) { msyyy[i] = w; w += SY; }
    for (int i = 0; i < 2; ++i) { msxyy[i] = w; w += SY; }
    for (int i = 0; i < 2; ++i) { msxyx[i] = w; w += SX; }
    for (int i = 0; i < 2; ++i) { msxxx[i] = w; w += SX; }
    float* mvyy = w; w += SY;
    float* mvxy = w; w += SY;
    float* mvyx = w; w += SX;
    float* mvxx = w; w += SX;

    size_t total_bytes = (size_t)(w - (float*)d_ws) * sizeof(float);
    // ws is poisoned 0xAA before every call — zero everything we use
    hipMemsetAsync(d_ws, 0, total_bytes, stream);
    init_profiles<<<2, 256, 0, stream>>>(pa, pb);

    SP sp[2];
    for (int par = 0; par < 2; ++par) {
        int o = par, n = par ^ 1;
        SP& p = sp[par];
        p.lamb = (const float*)d_in[0];
        p.mu   = (const float*)d_in[1];
        p.buoy = (const float*)d_in[2];
        p.amps = (const float*)d_in[3];
        p.srcloc = (const int*)d_in[4];
        p.recloc = (const int*)d_in[5];
        p.out = (float*)d_out;
        p.pa = pa; p.pb = pb;
        p.vy_o = vy[o];  p.vx_o = vx[o];  p.syy_o = syy[o]; p.sxy_o = sxy[o]; p.sxx_o = sxx[o];
        p.vy_n = vy[n];  p.vx_n = vx[n];  p.syy_n = syy[n]; p.sxy_n = sxy[n]; p.sxx_n = sxx[n];
        p.msyyy_o = msyyy[o]; p.msxyy_o = msxyy[o]; p.msyyy_n = msyyy[n]; p.msxyy_n = msxyy[n];
        p.msxyx_o = msxyx[o]; p.msxxx_o = msxxx[o]; p.msxyx_n = msxyx[n]; p.msxxx_n = msxxx[n];
        p.mvyy = mvyy; p.mvxy = mvxy; p.mvyx = mvyx; p.mvxx = mvxx;
    }

    for (int t = 0; t < NT; ++t) {
        step_kernel<<<dim3(NBLK), dim3(512), 0, stream>>>(sp[t & 1], t);
    }
}

// Round 6
// 926.220 us; speedup vs baseline: 8.4193x; 1.3857x over previous
//
#include <hip/hip_runtime.h>

#define NY 512
#define NX 512
#define NSHOT 4
#define NSRC 2
#define NREC 64
#define NT 32
#define DXF 5.0f
#define DTF 0.0005f
#define PML_W 20
#define C1F 1.125f
#define C2F (-1.0f/24.0f)

// One fused kernel per timestep. Band decomposition: 4 shots x 128 bands x 4 rows,
// 512 blocks (2/CU -> 16 waves/CU) x 512 threads (thread = x column). Velocity is
// computed on an extended band (rows y0-2..y0+5) into LDS, so the stress phase
// needs no neighbor's velocity writes. All fields read across block boundaries are
// ping-ponged, so the launch boundary is the only sync.
// PML m-fields live in compact strip arrays (sigma==0 -> m==0 outside strips).
#define RB 4          // interior rows per block
#define EB 8          // extended rows (RB + 4)
#define BANDS 128
#define NBLK (NSHOT * BANDS)

struct SP {
    const float *lamb, *mu, *buoy, *amps;
    const int *srcloc, *recloc;
    float *out;
    const float *pa, *pb;
    // ping-pong: read old, write new (interior cells only)
    const float *vy_o, *vx_o, *syy_o, *sxy_o, *sxx_o;
    float *vy_n, *vx_n, *syy_n, *sxy_n, *sxx_n;
    const float *msyyy_o, *msxyy_o;   // y-strips [shot][40][512]
    float *msyyy_n, *msxyy_n;
    const float *msxyx_o, *msxxx_o;   // x-strips [shot][512][40]
    float *msxyx_n, *msxxx_n;
    // owner-only, pointwise -> single buffer
    float *mvyy, *mvxy;               // y-strips
    float *mvyx, *mvxx;               // x-strips
};

__device__ __forceinline__ bool in_pml(int i) {
    return (i < PML_W) | (i >= NY - PML_W);
}

__device__ __forceinline__ float ldz(const float* __restrict__ f, int sbase, int y, int x) {
    return ((unsigned)y < (unsigned)NY && (unsigned)x < (unsigned)NX)
               ? f[sbase + y * NX + x] : 0.0f;
}

__global__ void init_profiles(float* __restrict__ pa, float* __restrict__ pb) {
    int i = blockIdx.x * blockDim.x + threadIdx.x;
    if (i >= NY) return;
    float w = (float)PML_W;
    float x = (float)i;
    float frac = fmaxf((w - x) / w, (x - (float)(NY - 1 - PML_W)) / w);
    frac = fminf(fmaxf(frac, 0.0f), 1.0f);
    float sigma = 3.0f * 3500.0f * 6.9077553f / (2.0f * w * DXF) * frac * frac;
    float alpha = 78.539816f; // pi * 25
    float b = __expf(-(sigma + alpha) * DTF);
    pb[i] = b;
    pa[i] = sigma / (sigma + alpha) * (b - 1.0f);
}

__global__ __launch_bounds__(512, 4) void step_kernel(SP p, int t) {
    const int blk  = blockIdx.x;
    const int s    = blk >> 7;              // shot
    const int band = blk & (BANDS - 1);
    const int y0   = band * RB;
    const int x    = threadIdx.x;           // 0..511
    const int sbase = s * NY * NX;
    const float inv_dx = 1.0f / DXF;

    __shared__ float vyt[EB][NX];
    __shared__ float vxt[EB][NX];

    const float axp = p.pa[x], bxp = p.pb[x];
    const bool  xpml = in_pml(x);
    const int   xsi  = (x < PML_W) ? x : x - (NY - 2 * PML_W);  // 0..39

    // ---- phase A: velocity on extended rows [y0-2, y0+RB+2) ----
#pragma unroll 2
    for (int r = 0; r < EB; ++r) {
        int y = y0 - 2 + r;
        float vyn = 0.0f, vxn = 0.0f;
        if ((unsigned)y < (unsigned)NY) {
            int idx = sbase + y * NX + x;

            // dsyy = diff_minus(syy, y): taps y-2..y+1
            float syy_0  = p.syy_o[idx];
            float syy_m1 = ldz(p.syy_o, sbase, y - 1, x);
            float syy_m2 = ldz(p.syy_o, sbase, y - 2, x);
            float syy_p1 = ldz(p.syy_o, sbase, y + 1, x);
            float dsyy = (C1F * (syy_0 - syy_m1) + C2F * (syy_p1 - syy_m2)) * inv_dx;

            // dsxy_x = diff_plus(sxy, x): taps x-1..x+2
            float sxy_0   = p.sxy_o[idx];
            float sxy_xm1 = ldz(p.sxy_o, sbase, y, x - 1);
            float sxy_xp1 = ldz(p.sxy_o, sbase, y, x + 1);
            float sxy_xp2 = ldz(p.sxy_o, sbase, y, x + 2);
            float dsxy_x = (C1F * (sxy_xp1 - sxy_0) + C2F * (sxy_xp2 - sxy_xm1)) * inv_dx;

            // dsxy_y = diff_plus(sxy, y): taps y-1..y+2
            float sxy_ym1 = ldz(p.sxy_o, sbase, y - 1, x);
            float sxy_yp1 = ldz(p.sxy_o, sbase, y + 1, x);
            float sxy_yp2 = ldz(p.sxy_o, sbase, y + 2, x);
            float dsxy_y = (C1F * (sxy_yp1 - sxy_0) + C2F * (sxy_yp2 - sxy_ym1)) * inv_dx;

            // dsxx = diff_minus(sxx, x): taps x-2..x+1
            float sxx_0   = p.sxx_o[idx];
            float sxx_xm1 = ldz(p.sxx_o, sbase, y, x - 1);
            float sxx_xm2 = ldz(p.sxx_o, sbase, y, x - 2);
            float sxx_xp1 = ldz(p.sxx_o, sbase, y, x + 1);
            float dsxx = (C1F * (sxx_0 - sxx_xm1) + C2F * (sxx_xp1 - sxx_xm2)) * inv_dx;

            bool own = (y >= y0) & (y < y0 + RB);

            float msyyy = 0.0f, msxyy = 0.0f;
            if (in_pml(y)) {
                int ysi = (y < PML_W) ? y : y - (NY - 2 * PML_W);
                int is = (s * 2 * PML_W + ysi) * NX + x;
                float ay = p.pa[y], by = p.pb[y];
                msyyy = by * p.msyyy_o[is] + ay * dsyy;
                msxyy = by * p.msxyy_o[is] + ay * dsxy_y;
                if (own) { p.msyyy_n[is] = msyyy; p.msxyy_n[is] = msxyy; }
            }
            float msxyx = 0.0f, msxxx = 0.0f;
            if (xpml) {
                int is = (s * NY + y) * 2 * PML_W + xsi;
                msxyx = bxp * p.msxyx_o[is] + axp * dsxy_x;
                msxxx = bxp * p.msxxx_o[is] + axp * dsxx;
                if (own) { p.msxyx_n[is] = msxyx; p.msxxx_n[is] = msxxx; }
            }

            float b = p.buoy[y * NX + x];
            vyn = p.vy_o[idx] + DTF * b * ((dsyy + msyyy) + (dsxy_x + msxyx));
            vxn = p.vx_o[idx] + DTF * b * ((dsxy_y + msxyy) + (dsxx + msxxx));

            // source injection (also on redundantly-computed halo rows)
#pragma unroll
            for (int i = 0; i < NSRC; ++i) {
                int sy = p.srcloc[(s * NSRC + i) * 2 + 0];
                int sx = p.srcloc[(s * NSRC + i) * 2 + 1];
                if (sy == y && sx == x)
                    vyn += p.amps[(s * NSRC + i) * NT + t] * DTF * b;
            }
            if (own) { p.vy_n[idx] = vyn; p.vx_n[idx] = vxn; }
        }
        vyt[r][x] = vyn;
        vxt[r][x] = vxn;
    }
    __syncthreads();

    // ---- receivers for this step: vy(t) post-injection, owner band only ----
    if (x < NREC) {
        int ry = p.recloc[(s * NREC + x) * 2 + 0];
        int rx = p.recloc[(s * NREC + x) * 2 + 1];
        if (ry >= y0 && ry < y0 + RB)
            p.out[(s * NREC + x) * NT + t] = vyt[ry - y0 + 2][rx];
    }

    // ---- phase B: stress on interior rows, velocities from LDS ----
#pragma unroll
    for (int r = 0; r < RB; ++r) {
        int y  = y0 + r;
        int lr = r + 2;
        int idx = sbase + y * NX + x;

        float vy0v = vyt[lr][x];
        float dvyy = (C1F * (vyt[lr + 1][x] - vy0v) + C2F * (vyt[lr + 2][x] - vyt[lr - 1][x])) * inv_dx;

        float vx0v = vxt[lr][x];
        float vx_xm1 = (x >= 1)   ? vxt[lr][x - 1] : 0.0f;
        float vx_xp1 = (x <= 510) ? vxt[lr][x + 1] : 0.0f;
        float vx_xp2 = (x <= 509) ? vxt[lr][x + 2] : 0.0f;
        float dvxx = (C1F * (vx_xp1 - vx0v) + C2F * (vx_xp2 - vx_xm1)) * inv_dx;

        float vy_xm1 = (x >= 1)   ? vyt[lr][x - 1] : 0.0f;
        float vy_xm2 = (x >= 2)   ? vyt[lr][x - 2] : 0.0f;
        float vy_xp1 = (x <= 510) ? vyt[lr][x + 1] : 0.0f;
        float dvyx = (C1F * (vy0v - vy_xm1) + C2F * (vy_xp1 - vy_xm2)) * inv_dx;

        float dvxy = (C1F * (vx0v - vxt[lr - 1][x]) + C2F * (vxt[lr + 1][x] - vxt[lr - 2][x])) * inv_dx;

        float mvyy = 0.0f, mvxy = 0.0f;
        if (in_pml(y)) {
            int ysi = (y < PML_W) ? y : y - (NY - 2 * PML_W);
            int is = (s * 2 * PML_W + ysi) * NX + x;
            float ay = p.pa[y], by = p.pb[y];
            mvyy = by * p.mvyy[is] + ay * dvyy; p.mvyy[is] = mvyy;
            mvxy = by * p.mvxy[is] + ay * dvxy; p.mvxy[is] = mvxy;
        }
        float mvxx = 0.0f, mvyx = 0.0f;
        if (xpml) {
            int is = (s * NY + y) * 2 * PML_W + xsi;
            mvxx = bxp * p.mvxx[is] + axp * dvxx; p.mvxx[is] = mvxx;
            mvyx = bxp * p.mvyx[is] + axp * dvyx; p.mvyx[is] = mvyx;
        }

        float tvyy = dvyy + mvyy;
        float tvxx = dvxx + mvxx;
        float la = p.lamb[y * NX + x];
        float m  = p.mu[y * NX + x];
        float l2m = la + 2.0f * m;
        p.syy_n[idx] = p.syy_o[idx] + DTF * (l2m * tvyy + la * tvxx);
        p.sxx_n[idx] = p.sxx_o[idx] + DTF * (l2m * tvxx + la * tvyy);
        p.sxy_n[idx] = p.sxy_o[idx] + DTF * m * ((dvyx + mvyx) + (dvxy + mvxy));
    }
}

extern "C" void kernel_launch(void* const* d_in, const int* in_sizes, int n_in,
                              void* d_out, int out_size, void* d_ws, size_t ws_size,
                              hipStream_t stream) {
    const size_t F  = (size_t)NSHOT * NY * NX;            // full field
    const size_t SY = (size_t)NSHOT * 2 * PML_W * NX;     // y-strip field
    const size_t SX = (size_t)NSHOT * NY * 2 * PML_W;     // x-strip field

    float* w = (float*)d_ws;
    float* pa = w; w += 512;
    float* pb = w; w += 512;
    float* vy[2];  float* vx[2];  float* syy[2]; float* sxy[2]; float* sxx[2];
    float* msyyy[2]; float* msxyy[2]; float* msxyx[2]; float* msxxx[2];
    for (int i = 0; i < 2; ++i) { vy[i]  = w; w += F; }
    for (int i = 0; i < 2; ++i) { vx[i]  = w; w += F; }
    for (int i = 0; i < 2; ++i) { syy[i] = w; w += F; }
    for (int i = 0; i < 2; ++i) { sxy[i] = w; w += F; }
    for (int i = 0; i < 2; ++i) { sxx[i] = w; w += F; }
    for (int i = 0; i < 2; ++i) { msyyy[i] = w; w += SY; }
    for (int i = 0; i < 2; ++i) { msxyy[i] = w; w += SY; }
    for (int i = 0; i < 2; ++i) { msxyx[i] = w; w += SX; }
    for (int i = 0; i < 2; ++i) { msxxx[i] = w; w += SX; }
    float* mvyy = w; w += SY;
    float* mvxy = w; w += SY;
    float* mvyx = w; w += SX;
    float* mvxx = w; w += SX;

    size_t total_bytes = (size_t)(w - (float*)d_ws) * sizeof(float);
    // ws is poisoned 0xAA before every call — zero everything we use
    hipMemsetAsync(d_ws, 0, total_bytes, stream);
    init_profiles<<<2, 256, 0, stream>>>(pa, pb);

    SP sp[2];
    for (int par = 0; par < 2; ++par) {
        int o = par, n = par ^ 1;
        SP& p = sp[par];
        p.lamb = (const float*)d_in[0];
        p.mu   = (const float*)d_in[1];
        p.buoy = (const float*)d_in[2];
        p.amps = (const float*)d_in[3];
        p.srcloc = (const int*)d_in[4];
        p.recloc = (const int*)d_in[5];
        p.out = (float*)d_out;
        p.pa = pa; p.pb = pb;
        p.vy_o = vy[o];  p.vx_o = vx[o];  p.syy_o = syy[o]; p.sxy_o = sxy[o]; p.sxx_o = sxx[o];
        p.vy_n = vy[n];  p.vx_n = vx[n];  p.syy_n = syy[n]; p.sxy_n = sxy[n]; p.sxx_n = sxx[n];
        p.msyyy_o = msyyy[o]; p.msxyy_o = msxyy[o]; p.msyyy_n = msyyy[n]; p.msxyy_n = msxyy[n];
        p.msxyx_o = msxyx[o]; p.msxxx_o = msxxx[o]; p.msxyx_n = msxyx[n]; p.msxxx_n = msxxx[n];
        p.mvyy = mvyy; p.mvxy = mvxy; p.mvyx = mvyx; p.mvxx = mvxx;
    }

    for (int t = 0; t < NT; ++t) {
        step_kernel<<<dim3(NBLK), dim3(512), 0, stream>>>(sp[t & 1], t);
    }
}

// Round 7
// 879.393 us; speedup vs baseline: 8.8676x; 1.0532x over previous
//
#include <hip/hip_runtime.h>

#define NY 512
#define NX 512
#define NSHOT 4
#define NSRC 2
#define NREC 64
#define NT 32
#define DXF 5.0f
#define DTF 0.0005f
#define PML_W 20
#define C1F 1.125f
#define C2F (-1.0f/24.0f)

// One fused kernel per timestep. 4 shots x 256 bands x 2 rows = 1024 blocks
// (4/CU -> up to 32 waves/CU at VGPR<=64) x 512 threads (thread = x column).
// Velocity is computed on an extended band (rows y0-2..y0+3) into LDS, so the
// stress phase needs no neighbor's velocity writes (3x redundant vel compute —
// cheap while latency-bound). Cross-block-read fields are ping-ponged; the
// launch boundary is the only sync. PML m-fields in compact strips.
#define RB 2          // interior rows per block
#define EB 6          // extended rows (RB + 4)
#define BANDS 256
#define NBLK (NSHOT * BANDS)

struct SP {
    const float *lamb, *mu, *buoy, *amps;
    const int *srcloc, *recloc;
    float *out;
    const float *pa, *pb;
    // ping-pong: read old, write new (interior cells only)
    const float *vy_o, *vx_o, *syy_o, *sxy_o, *sxx_o;
    float *vy_n, *vx_n, *syy_n, *sxy_n, *sxx_n;
    const float *msyyy_o, *msxyy_o;   // y-strips [shot][40][512]
    float *msyyy_n, *msxyy_n;
    const float *msxyx_o, *msxxx_o;   // x-strips [shot][512][40]
    float *msxyx_n, *msxxx_n;
    // owner-only, pointwise -> single buffer
    float *mvyy, *mvxy;               // y-strips
    float *mvyx, *mvxx;               // x-strips
};

__device__ __forceinline__ bool in_pml(int i) {
    return (i < PML_W) | (i >= NY - PML_W);
}

__device__ __forceinline__ float ldz(const float* __restrict__ f, int sbase, int y, int x) {
    return ((unsigned)y < (unsigned)NY && (unsigned)x < (unsigned)NX)
               ? f[sbase + y * NX + x] : 0.0f;
}

__global__ void init_profiles(float* __restrict__ pa, float* __restrict__ pb) {
    int i = blockIdx.x * blockDim.x + threadIdx.x;
    if (i >= NY) return;
    float w = (float)PML_W;
    float x = (float)i;
    float frac = fmaxf((w - x) / w, (x - (float)(NY - 1 - PML_W)) / w);
    frac = fminf(fmaxf(frac, 0.0f), 1.0f);
    float sigma = 3.0f * 3500.0f * 6.9077553f / (2.0f * w * DXF) * frac * frac;
    float alpha = 78.539816f; // pi * 25
    float b = __expf(-(sigma + alpha) * DTF);
    pb[i] = b;
    pa[i] = sigma / (sigma + alpha) * (b - 1.0f);
}

__global__ __launch_bounds__(512, 8) void step_kernel(SP p, int t) {
    const int blk  = blockIdx.x;
    const int s    = blk >> 8;              // shot
    const int band = blk & (BANDS - 1);
    const int y0   = band * RB;
    const int x    = threadIdx.x;           // 0..511
    const int sbase = s * NY * NX;
    const float inv_dx = 1.0f / DXF;

    __shared__ float vyt[EB][NX];
    __shared__ float vxt[EB][NX];

    const float axp = p.pa[x], bxp = p.pb[x];
    const bool  xpml = in_pml(x);
    const int   xsi  = (x < PML_W) ? x : x - (NY - 2 * PML_W);  // 0..39

    // hoist loop-invariant source data
    int sy0 = p.srcloc[(s * NSRC + 0) * 2 + 0];
    int sx0 = p.srcloc[(s * NSRC + 0) * 2 + 1];
    int sy1 = p.srcloc[(s * NSRC + 1) * 2 + 0];
    int sx1 = p.srcloc[(s * NSRC + 1) * 2 + 1];
    float amp0 = p.amps[(s * NSRC + 0) * NT + t];
    float amp1 = p.amps[(s * NSRC + 1) * NT + t];

    // ---- phase A: velocity on extended rows [y0-2, y0+RB+2) ----
#pragma unroll 2
    for (int r = 0; r < EB; ++r) {
        int y = y0 - 2 + r;
        float vyn = 0.0f, vxn = 0.0f;
        if ((unsigned)y < (unsigned)NY) {
            int idx = sbase + y * NX + x;

            // dsyy = diff_minus(syy, y): taps y-2..y+1
            float syy_0  = p.syy_o[idx];
            float syy_m1 = ldz(p.syy_o, sbase, y - 1, x);
            float syy_m2 = ldz(p.syy_o, sbase, y - 2, x);
            float syy_p1 = ldz(p.syy_o, sbase, y + 1, x);
            float dsyy = (C1F * (syy_0 - syy_m1) + C2F * (syy_p1 - syy_m2)) * inv_dx;

            // dsxy_x = diff_plus(sxy, x): taps x-1..x+2
            float sxy_0   = p.sxy_o[idx];
            float sxy_xm1 = ldz(p.sxy_o, sbase, y, x - 1);
            float sxy_xp1 = ldz(p.sxy_o, sbase, y, x + 1);
            float sxy_xp2 = ldz(p.sxy_o, sbase, y, x + 2);
            float dsxy_x = (C1F * (sxy_xp1 - sxy_0) + C2F * (sxy_xp2 - sxy_xm1)) * inv_dx;

            // dsxy_y = diff_plus(sxy, y): taps y-1..y+2
            float sxy_ym1 = ldz(p.sxy_o, sbase, y - 1, x);
            float sxy_yp1 = ldz(p.sxy_o, sbase, y + 1, x);
            float sxy_yp2 = ldz(p.sxy_o, sbase, y + 2, x);
            float dsxy_y = (C1F * (sxy_yp1 - sxy_0) + C2F * (sxy_yp2 - sxy_ym1)) * inv_dx;

            // dsxx = diff_minus(sxx, x): taps x-2..x+1
            float sxx_0   = p.sxx_o[idx];
            float sxx_xm1 = ldz(p.sxx_o, sbase, y, x - 1);
            float sxx_xm2 = ldz(p.sxx_o, sbase, y, x - 2);
            float sxx_xp1 = ldz(p.sxx_o, sbase, y, x + 1);
            float dsxx = (C1F * (sxx_0 - sxx_xm1) + C2F * (sxx_xp1 - sxx_xm2)) * inv_dx;

            bool own = (y >= y0) & (y < y0 + RB);

            float msyyy = 0.0f, msxyy = 0.0f;
            if (in_pml(y)) {
                int ysi = (y < PML_W) ? y : y - (NY - 2 * PML_W);
                int is = (s * 2 * PML_W + ysi) * NX + x;
                float ay = p.pa[y], by = p.pb[y];
                msyyy = by * p.msyyy_o[is] + ay * dsyy;
                msxyy = by * p.msxyy_o[is] + ay * dsxy_y;
                if (own) { p.msyyy_n[is] = msyyy; p.msxyy_n[is] = msxyy; }
            }
            float msxyx = 0.0f, msxxx = 0.0f;
            if (xpml) {
                int is = (s * NY + y) * 2 * PML_W + xsi;
                msxyx = bxp * p.msxyx_o[is] + axp * dsxy_x;
                msxxx = bxp * p.msxxx_o[is] + axp * dsxx;
                if (own) { p.msxyx_n[is] = msxyx; p.msxxx_n[is] = msxxx; }
            }

            float b = p.buoy[y * NX + x];
            vyn = p.vy_o[idx] + DTF * b * ((dsyy + msyyy) + (dsxy_x + msxyx));
            vxn = p.vx_o[idx] + DTF * b * ((dsxy_y + msxyy) + (dsxx + msxxx));

            // source injection (also on redundantly-computed halo rows)
            if (sy0 == y && sx0 == x) vyn += amp0 * DTF * b;
            if (sy1 == y && sx1 == x) vyn += amp1 * DTF * b;

            if (own) { p.vy_n[idx] = vyn; p.vx_n[idx] = vxn; }
        }
        vyt[r][x] = vyn;
        vxt[r][x] = vxn;
    }
    __syncthreads();

    // ---- receivers for this step: vy(t) post-injection, owner band only ----
    if (x < NREC) {
        int ry = p.recloc[(s * NREC + x) * 2 + 0];
        int rx = p.recloc[(s * NREC + x) * 2 + 1];
        if (ry >= y0 && ry < y0 + RB)
            p.out[(s * NREC + x) * NT + t] = vyt[ry - y0 + 2][rx];
    }

    // ---- phase B: stress on interior rows, velocities from LDS ----
#pragma unroll
    for (int r = 0; r < RB; ++r) {
        int y  = y0 + r;
        int lr = r + 2;
        int idx = sbase + y * NX + x;

        float vy0v = vyt[lr][x];
        float dvyy = (C1F * (vyt[lr + 1][x] - vy0v) + C2F * (vyt[lr + 2][x] - vyt[lr - 1][x])) * inv_dx;

        float vx0v = vxt[lr][x];
        float vx_xm1 = (x >= 1)   ? vxt[lr][x - 1] : 0.0f;
        float vx_xp1 = (x <= 510) ? vxt[lr][x + 1] : 0.0f;
        float vx_xp2 = (x <= 509) ? vxt[lr][x + 2] : 0.0f;
        float dvxx = (C1F * (vx_xp1 - vx0v) + C2F * (vx_xp2 - vx_xm1)) * inv_dx;

        float vy_xm1 = (x >= 1)   ? vyt[lr][x - 1] : 0.0f;
        float vy_xm2 = (x >= 2)   ? vyt[lr][x - 2] : 0.0f;
        float vy_xp1 = (x <= 510) ? vyt[lr][x + 1] : 0.0f;
        float dvyx = (C1F * (vy0v - vy_xm1) + C2F * (vy_xp1 - vy_xm2)) * inv_dx;

        float dvxy = (C1F * (vx0v - vxt[lr - 1][x]) + C2F * (vxt[lr + 1][x] - vxt[lr - 2][x])) * inv_dx;

        float mvyy = 0.0f, mvxy = 0.0f;
        if (in_pml(y)) {
            int ysi = (y < PML_W) ? y : y - (NY - 2 * PML_W);
            int is = (s * 2 * PML_W + ysi) * NX + x;
            float ay = p.pa[y], by = p.pb[y];
            mvyy = by * p.mvyy[is] + ay * dvyy; p.mvyy[is] = mvyy;
            mvxy = by * p.mvxy[is] + ay * dvxy; p.mvxy[is] = mvxy;
        }
        float mvxx = 0.0f, mvyx = 0.0f;
        if (xpml) {
            int is = (s * NY + y) * 2 * PML_W + xsi;
            mvxx = bxp * p.mvxx[is] + axp * dvxx; p.mvxx[is] = mvxx;
            mvyx = bxp * p.mvyx[is] + axp * dvyx; p.mvyx[is] = mvyx;
        }

        float tvyy = dvyy + mvyy;
        float tvxx = dvxx + mvxx;
        float la = p.lamb[y * NX + x];
        float m  = p.mu[y * NX + x];
        float l2m = la + 2.0f * m;
        p.syy_n[idx] = p.syy_o[idx] + DTF * (l2m * tvyy + la * tvxx);
        p.sxx_n[idx] = p.sxx_o[idx] + DTF * (l2m * tvxx + la * tvyy);
        p.sxy_n[idx] = p.sxy_o[idx] + DTF * m * ((dvyx + mvyx) + (dvxy + mvxy));
    }
}

extern "C" void kernel_launch(void* const* d_in, const int* in_sizes, int n_in,
                              void* d_out, int out_size, void* d_ws, size_t ws_size,
                              hipStream_t stream) {
    const size_t F  = (size_t)NSHOT * NY * NX;            // full field
    const size_t SY = (size_t)NSHOT * 2 * PML_W * NX;     // y-strip field
    const size_t SX = (size_t)NSHOT * NY * 2 * PML_W;     // x-strip field

    float* w = (float*)d_ws;
    float* pa = w; w += 512;
    float* pb = w; w += 512;
    float* vy[2];  float* vx[2];  float* syy[2]; float* sxy[2]; float* sxx[2];
    float* msyyy[2]; float* msxyy[2]; float* msxyx[2]; float* msxxx[2];
    for (int i = 0; i < 2; ++i) { vy[i]  = w; w += F; }
    for (int i = 0; i < 2; ++i) { vx[i]  = w; w += F; }
    for (int i = 0; i < 2; ++i) { syy[i] = w; w += F; }
    for (int i = 0; i < 2; ++i) { sxy[i] = w; w += F; }
    for (int i = 0; i < 2; ++i) { sxx[i] = w; w += F; }
    for (int i = 0; i < 2; ++i) { msyyy[i] = w; w += SY; }
    for (int i = 0; i < 2; ++i) { msxyy[i] = w; w += SY; }
    for (int i = 0; i < 2; ++i) { msxyx[i] = w; w += SX; }
    for (int i = 0; i < 2; ++i) { msxxx[i] = w; w += SX; }
    float* mvyy = w; w += SY;
    float* mvxy = w; w += SY;
    float* mvyx = w; w += SX;
    float* mvxx = w; w += SX;

    size_t total_bytes = (size_t)(w - (float*)d_ws) * sizeof(float);
    // ws is poisoned 0xAA before every call — zero everything we use
    hipMemsetAsync(d_ws, 0, total_bytes, stream);
    init_profiles<<<2, 256, 0, stream>>>(pa, pb);

    SP sp[2];
    for (int par = 0; par < 2; ++par) {
        int o = par, n = par ^ 1;
        SP& p = sp[par];
        p.lamb = (const float*)d_in[0];
        p.mu   = (const float*)d_in[1];
        p.buoy = (const float*)d_in[2];
        p.amps = (const float*)d_in[3];
        p.srcloc = (const int*)d_in[4];
        p.recloc = (const int*)d_in[5];
        p.out = (float*)d_out;
        p.pa = pa; p.pb = pb;
        p.vy_o = vy[o];  p.vx_o = vx[o];  p.syy_o = syy[o]; p.sxy_o = sxy[o]; p.sxx_o = sxx[o];
        p.vy_n = vy[n];  p.vx_n = vx[n];  p.syy_n = syy[n]; p.sxy_n = sxy[n]; p.sxx_n = sxx[n];
        p.msyyy_o = msyyy[o]; p.msxyy_o = msxyy[o]; p.msyyy_n = msyyy[n]; p.msxyy_n = msxyy[n];
        p.msxyx_o = msxyx[o]; p.msxxx_o = msxxx[o]; p.msxyx_n = msxyx[n]; p.msxxx_n = msxxx[n];
        p.mvyy = mvyy; p.mvxy = mvxy; p.mvyx = mvyx; p.mvxx = mvxx;
    }

    for (int t = 0; t < NT; ++t) {
        step_kernel<<<dim3(NBLK), dim3(512), 0, stream>>>(sp[t & 1], t);
    }
}